// Round 8
// baseline (316.187 us; speedup 1.0000x reference)
//
#include <hip/hip_runtime.h>
#include <hip/hip_fp16.h>

// GATConv (PyG, edge_dim, concat): N=100000, E=1e6, IN=64, H=4, C=32.
// fp32 inputs: x[N,64], edge_index (int32/int64, per-block ballot detect) [2,E],
// edge_attr[E,16], W[64,128], W_edge[16,128], att_src/dst/edge[4,32], bias[128].
// Output fp32 [N,128].
//
// Round 8: (a) k_place 4 edges/thread (4 independent atomic->store chains) +
// interleaved a_sd[8] node record (1 random line instead of 2); (b) k_gather
// channel phase: wave split by edge parity, 8B loads (4 ch/lane), 2 edges per
// iter, x2 unroll -> 4 edges in flight; (c) k_hist fused into k_proj.

#define HC 128
#define NEG 0.2f
#define NEG_INF (-3.0e38f)
#define CH 16

typedef __fp16 half2_t __attribute__((ext_vector_type(2)));

__device__ __forceinline__ unsigned short f2bf(float f) {
    unsigned u = __float_as_uint(f);
    return (unsigned short)((u + 0x7fffu + ((u >> 16) & 1u)) >> 16);  // RNE
}
__device__ __forceinline__ unsigned pk_h2(float lo, float hi) {
    half2_t p = __builtin_amdgcn_cvt_pkrtz(lo, hi);
    union { half2_t h; unsigned u; } cv;
    cv.h = p;
    return cv.u;
}
__device__ __forceinline__ float h2f_bits(unsigned short bits) {
    __half_raw hr; hr.x = bits;
    return __half2float(*reinterpret_cast<__half*>(&hr));
}
__device__ __forceinline__ long ld_idx(const int* __restrict__ ei, long i, int m64) {
    return m64 ? (long)(((const long long*)ei)[i]) : (long)ei[i];
}
// per-block int64 detect: int64 LE with values < 2^31 => odd 32-bit words zero.
// Call with >=64 threads before any divergent return (block-uniform branch ok).
__device__ __forceinline__ int detect_m64(const int* __restrict__ ei, int* s_m64) {
    int t = threadIdx.x;
    if (t < 64) {
        unsigned long long bal = __ballot(ei[2 * t + 1] != 0);
        if (t == 0) *s_m64 = (bal == 0ull) ? 1 : 0;
    }
    __syncthreads();
    return *s_m64;
}

// Fused: blocks [0,Np) do projection (64 nodes x 128 cols, 8x4 reg tile);
// blocks [Np,..) do destination histogram (4 edges/thread).
__global__ __launch_bounds__(256) void k_proj_hist(
    const float* __restrict__ x, const float* __restrict__ W,
    const float* __restrict__ as_, const float* __restrict__ ad_,
    unsigned short* __restrict__ xp, float* __restrict__ a_sd,
    const int* __restrict__ ei, int* __restrict__ deg,
    int N, int E, int Np) {
    __shared__ float x_s[64][68];
    __shared__ float W_s[64][128];
    int t = threadIdx.x;

    if (blockIdx.x >= Np) {
        // ---- histogram role ----
        int m64 = detect_m64(ei, (int*)&x_s[0][0]);
        int base = (blockIdx.x - Np) * 1024 + t;
        long d[4];
        bool val[4];
#pragma unroll
        for (int k = 0; k < 4; ++k) {
            int e = base + k * 256;
            val[k] = e < E;
            d[k] = val[k] ? ld_idx(ei, (long)E + e, m64) : 0;
        }
#pragma unroll
        for (int k = 0; k < 4; ++k)
            if (val[k]) atomicAdd(&deg[d[k]], 1);
        return;
    }

    // ---- projection role ----
    int n0 = blockIdx.x * 64;
#pragma unroll
    for (int i = 0; i < 8; ++i) {
        int fl = i * 256 + t;
        int k = fl >> 5, c4 = fl & 31;
        *reinterpret_cast<float4*>(&W_s[k][c4 * 4]) =
            *reinterpret_cast<const float4*>(&W[k * HC + c4 * 4]);
    }
#pragma unroll
    for (int i = 0; i < 4; ++i) {
        int fl = i * 256 + t;
        int node = fl >> 4, f4 = fl & 15;
        float4 v = make_float4(0.f, 0.f, 0.f, 0.f);
        if (n0 + node < N)
            v = *reinterpret_cast<const float4*>(&x[(long)(n0 + node) * 64 + f4 * 4]);
        x_s[f4 * 4 + 0][node] = v.x;
        x_s[f4 * 4 + 1][node] = v.y;
        x_s[f4 * 4 + 2][node] = v.z;
        x_s[f4 * 4 + 3][node] = v.w;
    }
    __syncthreads();

    int c = t & 31;
    int nd = t >> 5;
    float acc[8][4];
#pragma unroll
    for (int i = 0; i < 8; ++i)
#pragma unroll
        for (int j = 0; j < 4; ++j) acc[i][j] = 0.f;

    for (int k = 0; k < 64; ++k) {
        float4 w4 = *reinterpret_cast<const float4*>(&W_s[k][c * 4]);
        float4 xa = *reinterpret_cast<const float4*>(&x_s[k][nd * 8]);
        float4 xb = *reinterpret_cast<const float4*>(&x_s[k][nd * 8 + 4]);
        float xv[8] = {xa.x, xa.y, xa.z, xa.w, xb.x, xb.y, xb.z, xb.w};
#pragma unroll
        for (int i = 0; i < 8; ++i) {
            acc[i][0] += xv[i] * w4.x;
            acc[i][1] += xv[i] * w4.y;
            acc[i][2] += xv[i] * w4.z;
            acc[i][3] += xv[i] * w4.w;
        }
    }

    float4 s4 = *reinterpret_cast<const float4*>(&as_[c * 4]);
    float4 d4 = *reinterpret_cast<const float4*>(&ad_[c * 4]);
#pragma unroll
    for (int i = 0; i < 8; ++i) {
        int node = n0 + nd * 8 + i;
        if (node < N) {
            ushort4 o;
            o.x = f2bf(acc[i][0]); o.y = f2bf(acc[i][1]);
            o.z = f2bf(acc[i][2]); o.w = f2bf(acc[i][3]);
            *reinterpret_cast<ushort4*>(&xp[(long)node * HC + c * 4]) = o;
        }
        float ps = acc[i][0] * s4.x + acc[i][1] * s4.y + acc[i][2] * s4.z + acc[i][3] * s4.w;
        float pd = acc[i][0] * d4.x + acc[i][1] * d4.y + acc[i][2] * d4.z + acc[i][3] * d4.w;
#pragma unroll
        for (int off = 1; off < 8; off <<= 1) {
            ps += __shfl_xor(ps, off, 64);
            pd += __shfl_xor(pd, off, 64);
        }
        if ((c & 7) == 0 && node < N) {
            int h = c >> 3;
            a_sd[(long)node * 8 + h] = ps;       // a_src
            a_sd[(long)node * 8 + 4 + h] = pd;   // a_dst
        }
    }
}

__global__ __launch_bounds__(256) void k_scan1(
    const int* __restrict__ deg, int* __restrict__ row, int* __restrict__ bsum,
    int N) {
    __shared__ int s[256];
    int b = blockIdx.x, t = threadIdx.x;
    int base = b * 1024 + t * 4;
    int v[4], sum = 0;
#pragma unroll
    for (int i = 0; i < 4; ++i) {
        int idx = base + i;
        v[i] = (idx < N) ? deg[idx] : 0;
        sum += v[i];
    }
    s[t] = sum;
    __syncthreads();
    for (int off = 1; off < 256; off <<= 1) {
        int xv = (t >= off) ? s[t - off] : 0;
        __syncthreads();
        s[t] += xv;
        __syncthreads();
    }
    int run = s[t] - sum;
#pragma unroll
    for (int i = 0; i < 4; ++i) {
        int idx = base + i;
        if (idx < N) row[idx] = run;
        run += v[i];
    }
    if (t == 255) bsum[b] = s[255];
}

// wave 0: shfl scan over up to 128 block sums; wave 1: q[64] precompute.
__global__ void k_scan2(int* __restrict__ bsum, int nb,
                        const float* __restrict__ We, const float* __restrict__ ae,
                        float* __restrict__ q) {
    int t = threadIdx.x;
    if (t < 64) {
        int i0 = 2 * t, i1 = 2 * t + 1;
        int v0 = (i0 < nb) ? bsum[i0] : 0;
        int v1 = (i1 < nb) ? bsum[i1] : 0;
        int s = v0 + v1;
#pragma unroll
        for (int off = 1; off < 64; off <<= 1) {
            int u = __shfl_up(s, off, 64);
            if (t >= off) s += u;
        }
        int ex = s - (v0 + v1);
        if (i0 < nb) bsum[i0] = ex;
        if (i1 < nb) bsum[i1] = ex + v0;
    } else {
        int tt = t - 64;
        int d = tt >> 2, h = tt & 3;
        float s = 0.f;
        for (int c = 0; c < 32; ++c)
            s += We[d * HC + h * 32 + c] * ae[h * 32 + c];
        q[tt] = s;
    }
}

__global__ __launch_bounds__(256) void k_scan3(
    int* __restrict__ row, const int* __restrict__ bsum, int* __restrict__ cursor,
    int N, int E) {
    int i = blockIdx.x * blockDim.x + threadIdx.x;
    if (i < N) {
        int r = row[i] + bsum[i >> 10];
        row[i] = r;
        cursor[i] = r;
    }
    if (i == 0) row[N] = E;
}

// 4 edges/thread: full logit = leaky(a_src[s]+a_dst[d]+ea.q) fp16x4-packed
// with src into ONE 16B record at CSR position; 4 independent chains.
__global__ __launch_bounds__(256) void k_place(
    const int* __restrict__ ei, const float* __restrict__ ea,
    const float* __restrict__ q, const float* __restrict__ a_sd,
    int* __restrict__ cursor, uint4* __restrict__ srt, int E) {
    __shared__ int s_m64;
    int m64 = detect_m64(ei, &s_m64);
    int base = blockIdx.x * 1024 + threadIdx.x;

    long s[4], d[4];
    bool val[4];
    uint4 rec[4];
#pragma unroll
    for (int k = 0; k < 4; ++k) {
        int e = base + k * 256;
        val[k] = e < E;
        if (!val[k]) { s[k] = 0; d[k] = 0; continue; }
        s[k] = ld_idx(ei, e, m64);
        d[k] = ld_idx(ei, (long)E + e, m64);
    }
#pragma unroll
    for (int k = 0; k < 4; ++k) {
        if (!val[k]) { rec[k] = make_uint4(0, 0, 0, 0); continue; }
        int e = base + k * 256;
        const float4* pe = reinterpret_cast<const float4*>(ea + (long)e * 16);
        float4 e0 = pe[0], e1 = pe[1], e2 = pe[2], e3 = pe[3];
        float ev[16] = {e0.x, e0.y, e0.z, e0.w, e1.x, e1.y, e1.z, e1.w,
                        e2.x, e2.y, e2.z, e2.w, e3.x, e3.y, e3.z, e3.w};
        float4 s4 = *reinterpret_cast<const float4*>(a_sd + s[k] * 8);
        float4 d4 = *reinterpret_cast<const float4*>(a_sd + d[k] * 8 + 4);
        float sv[4] = {s4.x + d4.x, s4.y + d4.y, s4.z + d4.z, s4.w + d4.w};
        float ov[4];
#pragma unroll
        for (int h = 0; h < 4; ++h) {
            float aev = 0.f;
#pragma unroll
            for (int dd = 0; dd < 16; ++dd) aev += ev[dd] * q[dd * 4 + h];
            float al = sv[h] + aev;
            ov[h] = (al > 0.f) ? al : NEG * al;
        }
        rec[k] = make_uint4((unsigned)s[k], pk_h2(ov[0], ov[1]),
                            pk_h2(ov[2], ov[3]), 0u);
    }
    int pos[4];
#pragma unroll
    for (int k = 0; k < 4; ++k)
        pos[k] = val[k] ? atomicAdd(&cursor[d[k]], 1) : 0;
#pragma unroll
    for (int k = 0; k < 4; ++k)
        if (val[k]) srt[pos[k]] = rec[k];
}

// one wave per destination node; 2 nodes per 128-block.
// softmax phase: lane=(edge e=lane>>2, head h=lane&3), chunk=16 edges.
// channel phase: wave split by edge parity (lanes 0-31: even edge, 32-63: odd);
// lane owns 4 channels (8B bf16x4 load); 2 edges/iter, x2 unroll.
__global__ __launch_bounds__(128) void k_gather(
    const int* __restrict__ row, const uint4* __restrict__ srt,
    const char* __restrict__ xpc, const float* __restrict__ bias,
    float* __restrict__ out, int N) {
    int wid = threadIdx.x >> 6;
    int lane = threadIdx.x & 63;
    int n = blockIdx.x * 2 + wid;
    if (n >= N) return;
    int beg = row[n], end = row[n + 1];
    int h_s = lane & 3, e_s = lane >> 2;   // softmax role
    int par = lane >> 5;                   // channel-phase edge parity
    int cl = lane & 31;                    // channel quad: channels 4cl..4cl+3
    int h_a = cl >> 3;                     // head of those channels
    float m = NEG_INF, l = 0.f;
    float acc[4] = {0.f, 0.f, 0.f, 0.f};

    __shared__ float s_ex[2][CH][4];
    __shared__ int s_off[2][CH];
    __shared__ float s_bc[2][8];  // [0..3]=sc, [4..7]=l

    for (int cs = beg; cs < end; cs += CH) {
        int cnt = end - cs;
        if (cnt > CH) cnt = CH;
        float a = NEG_INF;
        if (e_s < cnt) {
            uint4 r = srt[cs + e_s];
            if (h_s == 0) s_off[wid][e_s] = (int)(r.x << 8);  // xp row byte off
            unsigned pr = (h_s & 2) ? r.z : r.y;
            unsigned bits = (h_s & 1) ? (pr >> 16) : (pr & 0xffffu);
            a = h2f_bits((unsigned short)bits);
        }
        float cm = a;
        cm = fmaxf(cm, __shfl_xor(cm, 4, 64));
        cm = fmaxf(cm, __shfl_xor(cm, 8, 64));
        cm = fmaxf(cm, __shfl_xor(cm, 16, 64));
        cm = fmaxf(cm, __shfl_xor(cm, 32, 64));
        float nm = fmaxf(m, cm);
        float ex = (e_s < cnt) ? __expf(a - nm) : 0.f;
        s_ex[wid][e_s][h_s] = ex;
        float se = ex;
        se += __shfl_xor(se, 4, 64);
        se += __shfl_xor(se, 8, 64);
        se += __shfl_xor(se, 16, 64);
        se += __shfl_xor(se, 32, 64);
        float sc = __expf(m - nm);
        l = l * sc + se;
        m = nm;
        if (lane < 4) s_bc[wid][h_s] = sc;  // lane<4 <=> e_s==0
        // single-wave lockstep: LDS writes above are program-ordered before
        // the reads below for all 64 lanes.
        float scl = s_bc[wid][h_a];
        acc[0] *= scl; acc[1] *= scl; acc[2] *= scl; acc[3] *= scl;
        int j = 0;
        for (; j + 4 <= cnt; j += 4) {
            int ea0 = j + par, ea1 = j + 2 + par;
            int o0 = s_off[wid][ea0], o1 = s_off[wid][ea1];
            float w0 = s_ex[wid][ea0][h_a], w1 = s_ex[wid][ea1][h_a];
            uint2 v0 = *reinterpret_cast<const uint2*>(xpc + o0 + cl * 8);
            uint2 v1 = *reinterpret_cast<const uint2*>(xpc + o1 + cl * 8);
            acc[0] += w0 * __uint_as_float(v0.x << 16);
            acc[1] += w0 * __uint_as_float(v0.x & 0xffff0000u);
            acc[2] += w0 * __uint_as_float(v0.y << 16);
            acc[3] += w0 * __uint_as_float(v0.y & 0xffff0000u);
            acc[0] += w1 * __uint_as_float(v1.x << 16);
            acc[1] += w1 * __uint_as_float(v1.x & 0xffff0000u);
            acc[2] += w1 * __uint_as_float(v1.y << 16);
            acc[3] += w1 * __uint_as_float(v1.y & 0xffff0000u);
        }
        for (; j < cnt; j += 2) {
            int e = j + par;
            bool act = e < cnt;
            int o = s_off[wid][act ? e : j];
            float w = act ? s_ex[wid][e][h_a] : 0.f;
            uint2 v = *reinterpret_cast<const uint2*>(xpc + o + cl * 8);
            acc[0] += w * __uint_as_float(v.x << 16);
            acc[1] += w * __uint_as_float(v.x & 0xffff0000u);
            acc[2] += w * __uint_as_float(v.y << 16);
            acc[3] += w * __uint_as_float(v.y & 0xffff0000u);
        }
    }
    if (lane < 4) s_bc[wid][4 + h_s] = l;
#pragma unroll
    for (int k = 0; k < 4; ++k) acc[k] += __shfl_xor(acc[k], 32, 64);
    if (par == 0) {
        float d = s_bc[wid][4 + h_a] + 1e-16f;
        float4 b4 = *reinterpret_cast<const float4*>(bias + cl * 4);
        float4 o;
        o.x = acc[0] / d + b4.x;
        o.y = acc[1] / d + b4.y;
        o.z = acc[2] / d + b4.z;
        o.w = acc[3] / d + b4.w;
        *reinterpret_cast<float4*>(out + (long)n * HC + cl * 4) = o;
    }
}

extern "C" void kernel_launch(void* const* d_in, const int* in_sizes, int n_in,
                              void* d_out, int out_size, void* d_ws, size_t ws_size,
                              hipStream_t stream) {
    const float* x    = (const float*)d_in[0];
    const int*   ei   = (const int*)d_in[1];
    const float* ea   = (const float*)d_in[2];
    const float* W    = (const float*)d_in[3];
    const float* We   = (const float*)d_in[4];
    const float* as_  = (const float*)d_in[5];
    const float* ad_  = (const float*)d_in[6];
    const float* ae   = (const float*)d_in[7];
    const float* bias = (const float*)d_in[8];
    float* out = (float*)d_out;

    int N = in_sizes[0] / 64;
    int E = in_sizes[1] / 2;

    char* ws = (char*)d_ws;
    size_t off = 0;
    auto take = [&](size_t bytes) -> char* {
        char* p = ws + off;
        off += (bytes + 511) & ~(size_t)511;
        return p;
    };
    unsigned short* xp = (unsigned short*)take((size_t)N * HC * 2);  // 25.6 MB
    float* a_sd    = (float*)take((size_t)N * 8 * 4);                // 3.2 MB
    uint4* srt     = (uint4*)take((size_t)E * 16);                   // 16 MB
    int* row       = (int*)take((size_t)(N + 1) * 4);
    int* cursor    = (int*)take((size_t)N * 4);
    int* bsum      = (int*)take(4096 * 4);
    float* qb      = (float*)take(64 * 4);
    int* deg       = (int*)take((size_t)N * 4);

    int Np = (N + 63) / 64;
    int Nh = (E + 1023) / 1024;
    int nblk = (N + 1023) / 1024;

    (void)hipMemsetAsync(deg, 0, (size_t)N * 4, stream);
    hipLaunchKernelGGL(k_proj_hist, dim3(Np + Nh), dim3(256), 0, stream,
                       x, W, as_, ad_, xp, a_sd, ei, deg, N, E, Np);
    hipLaunchKernelGGL(k_scan1, dim3(nblk), dim3(256), 0, stream, deg, row, bsum, N);
    hipLaunchKernelGGL(k_scan2, dim3(1), dim3(128), 0, stream, bsum, nblk, We, ae, qb);
    hipLaunchKernelGGL(k_scan3, dim3((N + 255) / 256), dim3(256), 0, stream,
                       row, bsum, cursor, N, E);
    hipLaunchKernelGGL(k_place, dim3((E + 1023) / 1024), dim3(256), 0, stream,
                       ei, ea, qb, a_sd, cursor, srt, E);
    hipLaunchKernelGGL(k_gather, dim3((N + 1) / 2), dim3(128), 0, stream,
                       row, srt, (const char*)xp, bias, out, N);
}

// Round 10
// 280.767 us; speedup vs baseline: 1.1262x; 1.1262x over previous
//
#include <hip/hip_runtime.h>
#include <hip/hip_fp16.h>

// GATConv (PyG, edge_dim, concat): N=100000, E=1e6, IN=64, H=4, C=32.
// fp32 inputs: x[N,64], edge_index (int32/int64, per-block ballot detect) [2,E],
// edge_attr[E,16], W[64,128], W_edge[16,128], att_src/dst/edge[4,32], bias[128].
// Output fp32 [N,128].
//
// Round 9b (compile fix: edge_attr param added to k_proj_hist).
// Rank trick — hist's atomicAdd return IS the CSR rank; store it, so k_place
// needs NO atomic (pos = row[d] + rank[e], fire-and-forget 16B store).
// ea·q precomputed as fp16x4 in the hist role (fused+interleaved with proj);
// place logit = a_src[s] + aev (a_dst + leaky applied in gather).

#define HC 128
#define NEG 0.2f
#define NEG_INF (-3.0e38f)
#define CH 16

typedef __fp16 half2_t __attribute__((ext_vector_type(2)));

__device__ __forceinline__ unsigned short f2bf(float f) {
    unsigned u = __float_as_uint(f);
    return (unsigned short)((u + 0x7fffu + ((u >> 16) & 1u)) >> 16);  // RNE
}
__device__ __forceinline__ unsigned pk_h2(float lo, float hi) {
    half2_t p = __builtin_amdgcn_cvt_pkrtz(lo, hi);
    union { half2_t h; unsigned u; } cv;
    cv.h = p;
    return cv.u;
}
__device__ __forceinline__ float h2f_bits(unsigned short bits) {
    __half_raw hr; hr.x = bits;
    return __half2float(*reinterpret_cast<__half*>(&hr));
}
__device__ __forceinline__ long ld_idx(const int* __restrict__ ei, long i, int m64) {
    return m64 ? (long)(((const long long*)ei)[i]) : (long)ei[i];
}
// per-block int64 detect: int64 LE with values < 2^31 => odd 32-bit words zero.
// Call with >=64 threads before any divergent return (block-uniform role ok).
__device__ __forceinline__ int detect_m64(const int* __restrict__ ei, int* s_m64) {
    int t = threadIdx.x;
    if (t < 64) {
        unsigned long long bal = __ballot(ei[2 * t + 1] != 0);
        if (t == 0) *s_m64 = (bal == 0ull) ? 1 : 0;
    }
    __syncthreads();
    return *s_m64;
}

// Fused, role-interleaved: proj (64 nodes x 128 cols, 8x4 reg tile) and
// hist (4 edges/thread: deg atomic -> rank, ea.q -> aev fp16x4).
// Block role: first 2*Nh blocks alternate (even=proj, odd=hist), rest proj.
__global__ __launch_bounds__(256) void k_proj_hist(
    const float* __restrict__ x, const float* __restrict__ W,
    const float* __restrict__ as_, const float* __restrict__ ad_,
    const float* __restrict__ We, const float* __restrict__ ae,
    const float* __restrict__ eattr,
    unsigned short* __restrict__ xp, float* __restrict__ a_src,
    float* __restrict__ a_dst, const int* __restrict__ ei,
    int* __restrict__ deg, int* __restrict__ rank, uint2* __restrict__ aeh,
    int N, int E, int Nh) {
    __shared__ float x_s[64][68];
    __shared__ float W_s[64][128];
    __shared__ float q_s[64];
    __shared__ int s_m64;
    int t = threadIdx.x;
    int id = blockIdx.x;

    bool hist_role = (id < 2 * Nh) && (id & 1);
    if (hist_role) {
        int hid = id >> 1;
        int m64 = detect_m64(ei, &s_m64);
        if (t < 64) {  // q[d*4+h] = sum_c We[d, h*32+c]*ae[h,c]
            int dd = t >> 2, h = t & 3;
            float s = 0.f;
            for (int c = 0; c < 32; ++c)
                s += We[dd * HC + h * 32 + c] * ae[h * 32 + c];
            q_s[t] = s;
        }
        __syncthreads();
        int base = hid * 1024 + t;
#pragma unroll
        for (int k = 0; k < 4; ++k) {
            int e = base + k * 256;
            if (e >= E) continue;
            long d = ld_idx(ei, (long)E + e, m64);
            const float4* pe = reinterpret_cast<const float4*>(eattr + (long)e * 16);
            float4 e0 = pe[0], e1 = pe[1], e2 = pe[2], e3 = pe[3];
            float ev[16] = {e0.x, e0.y, e0.z, e0.w, e1.x, e1.y, e1.z, e1.w,
                            e2.x, e2.y, e2.z, e2.w, e3.x, e3.y, e3.z, e3.w};
            float ov[4];
#pragma unroll
            for (int h = 0; h < 4; ++h) {
                float aev = 0.f;
#pragma unroll
                for (int dd = 0; dd < 16; ++dd) aev += ev[dd] * q_s[dd * 4 + h];
                ov[h] = aev;
            }
            aeh[e] = make_uint2(pk_h2(ov[0], ov[1]), pk_h2(ov[2], ov[3]));
            rank[e] = atomicAdd(&deg[d], 1);  // the CSR rank, for free
        }
        return;
    }

    // ---- projection role ----
    int pid = (id < 2 * Nh) ? (id >> 1) : (id - Nh);
    int n0 = pid * 64;
#pragma unroll
    for (int i = 0; i < 8; ++i) {
        int fl = i * 256 + t;
        int k = fl >> 5, c4 = fl & 31;
        *reinterpret_cast<float4*>(&W_s[k][c4 * 4]) =
            *reinterpret_cast<const float4*>(&W[k * HC + c4 * 4]);
    }
#pragma unroll
    for (int i = 0; i < 4; ++i) {
        int fl = i * 256 + t;
        int node = fl >> 4, f4 = fl & 15;
        float4 v = make_float4(0.f, 0.f, 0.f, 0.f);
        if (n0 + node < N)
            v = *reinterpret_cast<const float4*>(&x[(long)(n0 + node) * 64 + f4 * 4]);
        x_s[f4 * 4 + 0][node] = v.x;
        x_s[f4 * 4 + 1][node] = v.y;
        x_s[f4 * 4 + 2][node] = v.z;
        x_s[f4 * 4 + 3][node] = v.w;
    }
    __syncthreads();

    int c = t & 31;
    int nd = t >> 5;
    float acc[8][4];
#pragma unroll
    for (int i = 0; i < 8; ++i)
#pragma unroll
        for (int j = 0; j < 4; ++j) acc[i][j] = 0.f;

    for (int k = 0; k < 64; ++k) {
        float4 w4 = *reinterpret_cast<const float4*>(&W_s[k][c * 4]);
        float4 xa = *reinterpret_cast<const float4*>(&x_s[k][nd * 8]);
        float4 xb = *reinterpret_cast<const float4*>(&x_s[k][nd * 8 + 4]);
        float xv[8] = {xa.x, xa.y, xa.z, xa.w, xb.x, xb.y, xb.z, xb.w};
#pragma unroll
        for (int i = 0; i < 8; ++i) {
            acc[i][0] += xv[i] * w4.x;
            acc[i][1] += xv[i] * w4.y;
            acc[i][2] += xv[i] * w4.z;
            acc[i][3] += xv[i] * w4.w;
        }
    }

    float4 s4 = *reinterpret_cast<const float4*>(&as_[c * 4]);
    float4 d4 = *reinterpret_cast<const float4*>(&ad_[c * 4]);
#pragma unroll
    for (int i = 0; i < 8; ++i) {
        int node = n0 + nd * 8 + i;
        if (node < N) {
            ushort4 o;
            o.x = f2bf(acc[i][0]); o.y = f2bf(acc[i][1]);
            o.z = f2bf(acc[i][2]); o.w = f2bf(acc[i][3]);
            *reinterpret_cast<ushort4*>(&xp[(long)node * HC + c * 4]) = o;
        }
        float ps = acc[i][0] * s4.x + acc[i][1] * s4.y + acc[i][2] * s4.z + acc[i][3] * s4.w;
        float pd = acc[i][0] * d4.x + acc[i][1] * d4.y + acc[i][2] * d4.z + acc[i][3] * d4.w;
#pragma unroll
        for (int off = 1; off < 8; off <<= 1) {
            ps += __shfl_xor(ps, off, 64);
            pd += __shfl_xor(pd, off, 64);
        }
        if ((c & 7) == 0 && node < N) {
            int h = c >> 3;
            a_src[(long)node * 4 + h] = ps;
            a_dst[(long)node * 4 + h] = pd;
        }
    }
}

__global__ __launch_bounds__(256) void k_scan1(
    const int* __restrict__ deg, int* __restrict__ row, int* __restrict__ bsum,
    int N) {
    __shared__ int s[256];
    int b = blockIdx.x, t = threadIdx.x;
    int base = b * 1024 + t * 4;
    int v[4], sum = 0;
#pragma unroll
    for (int i = 0; i < 4; ++i) {
        int idx = base + i;
        v[i] = (idx < N) ? deg[idx] : 0;
        sum += v[i];
    }
    s[t] = sum;
    __syncthreads();
    for (int off = 1; off < 256; off <<= 1) {
        int xv = (t >= off) ? s[t - off] : 0;
        __syncthreads();
        s[t] += xv;
        __syncthreads();
    }
    int run = s[t] - sum;
#pragma unroll
    for (int i = 0; i < 4; ++i) {
        int idx = base + i;
        if (idx < N) row[idx] = run;
        run += v[i];
    }
    if (t == 255) bsum[b] = s[255];
}

// one-wave shfl scan over up to 128 block sums
__global__ void k_scan2(int* __restrict__ bsum, int nb) {
    int t = threadIdx.x;
    if (t >= 64) return;
    int i0 = 2 * t, i1 = 2 * t + 1;
    int v0 = (i0 < nb) ? bsum[i0] : 0;
    int v1 = (i1 < nb) ? bsum[i1] : 0;
    int s = v0 + v1;
#pragma unroll
    for (int off = 1; off < 64; off <<= 1) {
        int u = __shfl_up(s, off, 64);
        if (t >= off) s += u;
    }
    int ex = s - (v0 + v1);
    if (i0 < nb) bsum[i0] = ex;
    if (i1 < nb) bsum[i1] = ex + v0;
}

__global__ __launch_bounds__(256) void k_scan3(
    int* __restrict__ row, const int* __restrict__ bsum, int N, int E) {
    int i = blockIdx.x * blockDim.x + threadIdx.x;
    if (i < N) row[i] = row[i] + bsum[i >> 10];
    if (i == 0) row[N] = E;
}

// NO atomics: pos = row[d] + rank[e]. Record = {src, fp16x4 (a_src[s]+aev)}.
// 2 edges/thread (stride 256), fire-and-forget stores.
__global__ __launch_bounds__(256) void k_place(
    const int* __restrict__ ei, const uint2* __restrict__ aeh,
    const int* __restrict__ rank, const float* __restrict__ a_src,
    const int* __restrict__ row, uint4* __restrict__ srt, int E) {
    __shared__ int s_m64;
    int m64 = detect_m64(ei, &s_m64);
    int base = blockIdx.x * 512 + threadIdx.x;
#pragma unroll
    for (int k = 0; k < 2; ++k) {
        int e = base + k * 256;
        if (e >= E) continue;
        long s = ld_idx(ei, e, m64);
        long d = ld_idx(ei, (long)E + e, m64);
        uint2 av = aeh[e];
        int r = rank[e];
        float4 s4 = *reinterpret_cast<const float4*>(a_src + s * 4);
        float l0 = s4.x + h2f_bits((unsigned short)(av.x & 0xffffu));
        float l1 = s4.y + h2f_bits((unsigned short)(av.x >> 16));
        float l2 = s4.z + h2f_bits((unsigned short)(av.y & 0xffffu));
        float l3 = s4.w + h2f_bits((unsigned short)(av.y >> 16));
        int pos = row[d] + r;
        srt[pos] = make_uint4((unsigned)s, pk_h2(l0, l1), pk_h2(l2, l3), 0u);
    }
}

// one wave per destination node; 2 nodes per 128-block.
// softmax phase: lane=(edge e=lane>>2, head h=lane&3); logit = rec + a_dst,
// then leaky. channel phase: wave split by edge parity, 8B bf16x4 loads.
__global__ __launch_bounds__(128) void k_gather(
    const int* __restrict__ row, const uint4* __restrict__ srt,
    const float* __restrict__ a_dst, const char* __restrict__ xpc,
    const float* __restrict__ bias, float* __restrict__ out, int N) {
    int wid = threadIdx.x >> 6;
    int lane = threadIdx.x & 63;
    int n = blockIdx.x * 2 + wid;
    if (n >= N) return;
    int beg = row[n], end = row[n + 1];
    int h_s = lane & 3, e_s = lane >> 2;   // softmax role
    int par = lane >> 5;                   // channel-phase edge parity
    int cl = lane & 31;                    // channel quad: channels 4cl..4cl+3
    int h_a = cl >> 3;                     // head of those channels
    float adv = a_dst[(long)n * 4 + h_s];
    float m = NEG_INF, l = 0.f;
    float acc[4] = {0.f, 0.f, 0.f, 0.f};

    __shared__ float s_ex[2][CH][4];
    __shared__ int s_off[2][CH];
    __shared__ float s_bc[2][8];  // [0..3]=sc, [4..7]=l

    for (int cs = beg; cs < end; cs += CH) {
        int cnt = end - cs;
        if (cnt > CH) cnt = CH;
        float a = NEG_INF;
        if (e_s < cnt) {
            uint4 r = srt[cs + e_s];
            if (h_s == 0) s_off[wid][e_s] = (int)(r.x << 8);  // xp row byte off
            unsigned pr = (h_s & 2) ? r.z : r.y;
            unsigned bits = (h_s & 1) ? (pr >> 16) : (pr & 0xffffu);
            float v = h2f_bits((unsigned short)bits) + adv;
            a = (v > 0.f) ? v : NEG * v;
        }
        float cm = a;
        cm = fmaxf(cm, __shfl_xor(cm, 4, 64));
        cm = fmaxf(cm, __shfl_xor(cm, 8, 64));
        cm = fmaxf(cm, __shfl_xor(cm, 16, 64));
        cm = fmaxf(cm, __shfl_xor(cm, 32, 64));
        float nm = fmaxf(m, cm);
        float ex = (e_s < cnt) ? __expf(a - nm) : 0.f;
        s_ex[wid][e_s][h_s] = ex;
        float se = ex;
        se += __shfl_xor(se, 4, 64);
        se += __shfl_xor(se, 8, 64);
        se += __shfl_xor(se, 16, 64);
        se += __shfl_xor(se, 32, 64);
        float sc = __expf(m - nm);
        l = l * sc + se;
        m = nm;
        if (lane < 4) s_bc[wid][h_s] = sc;  // lane<4 <=> e_s==0
        // single-wave lockstep: LDS writes above are program-ordered before
        // the reads below for all 64 lanes.
        float scl = s_bc[wid][h_a];
        acc[0] *= scl; acc[1] *= scl; acc[2] *= scl; acc[3] *= scl;
        int j = 0;
        for (; j + 4 <= cnt; j += 4) {
            int ea0 = j + par, ea1 = j + 2 + par;
            int o0 = s_off[wid][ea0], o1 = s_off[wid][ea1];
            float w0 = s_ex[wid][ea0][h_a], w1 = s_ex[wid][ea1][h_a];
            uint2 v0 = *reinterpret_cast<const uint2*>(xpc + o0 + cl * 8);
            uint2 v1 = *reinterpret_cast<const uint2*>(xpc + o1 + cl * 8);
            acc[0] += w0 * __uint_as_float(v0.x << 16);
            acc[1] += w0 * __uint_as_float(v0.x & 0xffff0000u);
            acc[2] += w0 * __uint_as_float(v0.y << 16);
            acc[3] += w0 * __uint_as_float(v0.y & 0xffff0000u);
            acc[0] += w1 * __uint_as_float(v1.x << 16);
            acc[1] += w1 * __uint_as_float(v1.x & 0xffff0000u);
            acc[2] += w1 * __uint_as_float(v1.y << 16);
            acc[3] += w1 * __uint_as_float(v1.y & 0xffff0000u);
        }
        for (; j < cnt; j += 2) {
            int e = j + par;
            bool act = e < cnt;
            int o = s_off[wid][act ? e : j];
            float w = act ? s_ex[wid][e][h_a] : 0.f;
            uint2 v = *reinterpret_cast<const uint2*>(xpc + o + cl * 8);
            acc[0] += w * __uint_as_float(v.x << 16);
            acc[1] += w * __uint_as_float(v.x & 0xffff0000u);
            acc[2] += w * __uint_as_float(v.y << 16);
            acc[3] += w * __uint_as_float(v.y & 0xffff0000u);
        }
    }
    if (lane < 4) s_bc[wid][4 + h_s] = l;
#pragma unroll
    for (int k = 0; k < 4; ++k) acc[k] += __shfl_xor(acc[k], 32, 64);
    if (par == 0) {
        float d = s_bc[wid][4 + h_a] + 1e-16f;
        float4 b4 = *reinterpret_cast<const float4*>(bias + cl * 4);
        float4 o;
        o.x = acc[0] / d + b4.x;
        o.y = acc[1] / d + b4.y;
        o.z = acc[2] / d + b4.z;
        o.w = acc[3] / d + b4.w;
        *reinterpret_cast<float4*>(out + (long)n * HC + cl * 4) = o;
    }
}

extern "C" void kernel_launch(void* const* d_in, const int* in_sizes, int n_in,
                              void* d_out, int out_size, void* d_ws, size_t ws_size,
                              hipStream_t stream) {
    const float* x    = (const float*)d_in[0];
    const int*   ei   = (const int*)d_in[1];
    const float* ea   = (const float*)d_in[2];
    const float* W    = (const float*)d_in[3];
    const float* We   = (const float*)d_in[4];
    const float* as_  = (const float*)d_in[5];
    const float* ad_  = (const float*)d_in[6];
    const float* ae   = (const float*)d_in[7];
    const float* bias = (const float*)d_in[8];
    float* out = (float*)d_out;

    int N = in_sizes[0] / 64;
    int E = in_sizes[1] / 2;

    char* ws = (char*)d_ws;
    size_t off = 0;
    auto take = [&](size_t bytes) -> char* {
        char* p = ws + off;
        off += (bytes + 511) & ~(size_t)511;
        return p;
    };
    unsigned short* xp = (unsigned short*)take((size_t)N * HC * 2);  // 25.6 MB
    float* a_src   = (float*)take((size_t)N * 4 * 4);                // 1.6 MB
    float* a_dst   = (float*)take((size_t)N * 4 * 4);                // 1.6 MB
    uint4* srt     = (uint4*)take((size_t)E * 16);                   // 16 MB
    uint2* aeh     = (uint2*)take((size_t)E * 8);                    // 8 MB
    int* rank      = (int*)take((size_t)E * 4);                      // 4 MB
    int* row       = (int*)take((size_t)(N + 1) * 4);
    int* bsum      = (int*)take(4096 * 4);
    int* deg       = (int*)take((size_t)N * 4);

    int Np = (N + 63) / 64;
    int Nh = (E + 1023) / 1024;
    int nblk = (N + 1023) / 1024;

    (void)hipMemsetAsync(deg, 0, (size_t)N * 4, stream);
    hipLaunchKernelGGL(k_proj_hist, dim3(Np + Nh), dim3(256), 0, stream,
                       x, W, as_, ad_, We, ae, ea, xp, a_src, a_dst,
                       ei, deg, rank, aeh, N, E, Nh);
    hipLaunchKernelGGL(k_scan1, dim3(nblk), dim3(256), 0, stream, deg, row, bsum, N);
    hipLaunchKernelGGL(k_scan2, dim3(1), dim3(64), 0, stream, bsum, nblk);
    hipLaunchKernelGGL(k_scan3, dim3((N + 255) / 256), dim3(256), 0, stream,
                       row, bsum, N, E);
    hipLaunchKernelGGL(k_place, dim3((E + 511) / 512), dim3(256), 0, stream,
                       ei, aeh, rank, a_src, row, srt, E);
    hipLaunchKernelGGL(k_gather, dim3((N + 1) / 2), dim3(128), 0, stream,
                       row, srt, a_dst, (const char*)xp, bias, out, N);
}